// Round 8
// baseline (135.866 us; speedup 1.0000x reference)
//
#include <hip/hip_runtime.h>
#include <stdint.h>

// Problem constants (from reference setup_inputs)
#define BB    8
#define NN    16384
#define KK    1024
#define KNN   16
#define QTR   (NN / 4)    // each of 4 waves per pair owns a quarter
#define PILOT 2048        // pilot subset of the quarter for the bound T
#define HCAP  128         // survivor slots per (center, quarter); expected ~30

typedef unsigned long long u64;

// Manual 64-bit shuffle-xor (two 32-bit shuffles).
__device__ __forceinline__ u64 shfl_xor_u64(u64 v, int mask) {
    int lo = (int)(uint32_t)v;
    int hi = (int)(uint32_t)(v >> 32);
    lo = __shfl_xor(lo, mask, 64);
    hi = __shfl_xor(hi, mask, 64);
    return ((u64)(uint32_t)hi << 32) | (u64)(uint32_t)lo;
}

// Butterfly min over all 64 lanes; every lane ends with the wave minimum.
__device__ __forceinline__ u64 wave_min_u64(u64 v) {
#pragma unroll
    for (int off = 32; off > 0; off >>= 1) {
        u64 o = shfl_xor_u64(v, off);
        v = o < v ? o : v;
    }
    return v;
}

// Pack (x, y, z, ||x||^2) into aligned float4.
// x_sq per reference: (x0*x0 + x1*x1) + x2*x2, NO fma contraction.
__global__ __launch_bounds__(256) void prep_kernel(const float* __restrict__ xyz,
                                                   float4* __restrict__ pts) {
#pragma clang fp contract(off)
    int i = blockIdx.x * 256 + threadIdx.x;
    if (i < BB * NN) {
        float x0 = xyz[i * 3 + 0];
        float x1 = xyz[i * 3 + 1];
        float x2 = xyz[i * 3 + 2];
        float xsq = (x0 * x0 + x1 * x1) + x2 * x2;
        pts[i] = make_float4(x0, x1, x2, xsq);
    }
}

// EXACT reference d2 (final ranking + fallback): cross = sequential FMA chain
// (einsum -> dot_general -> BLAS microkernel semantics, verified R3); the
// rest plain fp32 ops, no contraction.
template <bool PACKED>
__device__ __forceinline__ float point_d2(const float4* pb, const float* xb, int i,
                                          float c0, float c1, float c2, float csq) {
#pragma clang fp contract(off)
    float x0, x1, x2, xsq;
    if (PACKED) {
        float4 p = pb[i];
        x0 = p.x; x1 = p.y; x2 = p.z; xsq = p.w;
    } else {
        x0 = xb[i * 3 + 0];
        x1 = xb[i * 3 + 1];
        x2 = xb[i * 3 + 2];
        xsq = (x0 * x0 + x1 * x1) + x2 * x2;
    }
    float cross = __fmaf_rn(x2, c2, __fmaf_rn(x1, c1, x0 * c0));
    float d2 = (xsq + csq) - 2.0f * cross;
    return d2 < 0.0f ? 0.0f : d2;   // jnp.maximum(d2, 0)
}

// Cold-path exact fallback (full-N bubble scan), only on buffer/cap overflow.
template <bool PACKED>
__device__ __attribute__((noinline)) int fallback_scan(const float4* pb, const float* xb,
                                                       float c0, float c1, float c2,
                                                       float csq, int lane) {
    u64 list[KNN];
#pragma unroll
    for (int j = 0; j < KNN; ++j) list[j] = ~0ull;
    for (int i = lane; i < NN; i += 64) {
        float d2 = point_d2<PACKED>(pb, xb, i, c0, c1, c2, csq);
        float dist = __fsqrt_rn(d2);
        u64 key = ((u64)__float_as_uint(dist) << 32) | (u64)(uint32_t)i;
        if (key < list[KNN - 1]) {
#pragma unroll
            for (int j = 0; j < KNN; ++j) {
                bool lt = key < list[j];
                u64 lo = lt ? key : list[j];
                u64 hi = lt ? list[j] : key;
                list[j] = lo;
                key = hi;
            }
        }
    }
    int res = 0;
    for (int it = 0; it < KNN; ++it) {
        u64 best = wave_min_u64(list[0]);
        if (it == lane) res = (int)(uint32_t)best;
        if (list[0] == best) {
#pragma unroll
            for (int j = 0; j < KNN - 1; ++j) list[j] = list[j + 1];
            list[KNN - 1] = ~0ull;
        }
    }
    return res;
}

// 16th-smallest FLOAT (true float order incl. negatives) of the 64 lane
// values, via full bitonic sort across lanes; lane 15 holds the answer.
__device__ __forceinline__ float sixteenth_smallest(float m, int lane) {
    uint32_t u = __float_as_uint(m);
    uint32_t s = (u & 0x80000000u) ? ~u : (u | 0x80000000u);  // sortable bits
    u64 v = ((u64)s << 32) | (unsigned)lane;                  // unique keys
#pragma unroll
    for (int k = 2; k <= 64; k <<= 1) {
#pragma unroll
        for (int j = k >> 1; j > 0; j >>= 1) {
            u64 o = shfl_xor_u64(v, j);
            bool up = (lane & k) == 0;          // k=64: ascending
            bool takeMin = ((lane & j) == 0) == up;
            u64 mn = v < o ? v : o;
            u64 mx = v < o ? o : v;
            v = takeMin ? mn : mx;
        }
    }
    uint32_t sb = (uint32_t)__shfl((int)(uint32_t)(v >> 32), 15, 64);
    uint32_t ub = (sb & 0x80000000u) ? (sb ^ 0x80000000u) : ~sb;
    return __uint_as_float(ub);
}

// FOUR waves per center-pair, each owning a QUARTER of the points
// (16384 waves total -> 8 waves/SIMD with halved per-wave scan work vs R7).
//   Phase 1 (pilot): per-lane min of d' = xs - 2*x.c over the first PILOT
//     points of this quarter -> T_q = 16th-smallest lane-min (>=16 real
//     points of the quarter have d' <= T_q). T = min over 4 quarters (LDS).
//   Phase 2 (filter): scan the quarter (64 iters); keep d' <= U = T +
//     |T|*1e-5 + 5e-4 (margin family verified R5-R7). Compact into LDS.
//   Phase 3: wave 0 reranks center A, wave 1 center B over all 4 quarter
//     buffers (total <= 256 -> <= 4 keys/lane, depth-4 exact); waves 2,3
//     retire. Verified (sqrt_rn-dist bits, idx) u64 key, 16-round pop-merge.
template <bool PACKED>
__global__ __launch_bounds__(256, 8) void knn_kernel(const float4* __restrict__ pts,
                                                     const float* __restrict__ xyz,
                                                     const float* __restrict__ centers,
                                                     int* __restrict__ out) {
#pragma clang fp contract(off)
    const int q = (int)(threadIdx.x >> 6);    // wave within block = quarter 0..3
    const int lane = (int)(threadIdx.x & 63);
    const int pair = (int)blockIdx.x;         // 0..4095
    const int b = pair >> 9;                  // 512 pairs per batch
    const int cA = (pair & 511) * 2;
    const int cB = cA + 1;

    __shared__ float    s_T[2][4];            // [center][quarter]
    __shared__ int      s_cnt[2][4];          // [center][quarter]
    __shared__ uint32_t s_idx[2][4][HCAP];    // [center][quarter][slot] 4 KB

    const float a0 = centers[(b * KK + cA) * 3 + 0];
    const float a1 = centers[(b * KK + cA) * 3 + 1];
    const float a2 = centers[(b * KK + cA) * 3 + 2];
    const float b0 = centers[(b * KK + cB) * 3 + 0];
    const float b1 = centers[(b * KK + cB) * 3 + 1];
    const float b2 = centers[(b * KK + cB) * 3 + 2];
    const float csqA = (a0 * a0 + a1 * a1) + a2 * a2;  // exact non-FMA (phase 3)
    const float csqB = (b0 * b0 + b1 * b1) + b2 * b2;
    const float nA0 = -2.0f * a0, nA1 = -2.0f * a1, nA2 = -2.0f * a2;  // exact
    const float nB0 = -2.0f * b0, nB1 = -2.0f * b1, nB2 = -2.0f * b2;

    const float4* pb = pts + (size_t)b * NN;
    const float* xb = xyz + (size_t)b * NN * 3;
    const int base = q * QTR;

    // ---- Phase 1: per-lane min of d' over the pilot subset of this quarter ----
    float mA = __builtin_inff(), mB = __builtin_inff();
#pragma unroll 4
    for (int i = base + lane; i < base + PILOT; i += 64) {
        float x0, x1, x2, xs;
        if (PACKED) {
            float4 p = pb[i];
            x0 = p.x; x1 = p.y; x2 = p.z; xs = p.w;
        } else {
            x0 = xb[i * 3 + 0];
            x1 = xb[i * 3 + 1];
            x2 = xb[i * 3 + 2];
            xs = (x0 * x0 + x1 * x1) + x2 * x2;
        }
        float dA = __fmaf_rn(x0, nA0, __fmaf_rn(x1, nA1, __fmaf_rn(x2, nA2, xs)));
        float dB = __fmaf_rn(x0, nB0, __fmaf_rn(x1, nB1, __fmaf_rn(x2, nB2, xs)));
        mA = dA < mA ? dA : mA;
        mB = dB < mB ? dB : mB;
    }

    {
        float tA = sixteenth_smallest(mA, lane);
        float tB = sixteenth_smallest(mB, lane);
        if (lane == 0) {
            s_T[0][q] = tA;
            s_T[1][q] = tB;
        }
    }
    __syncthreads();
    const float TA = fminf(fminf(s_T[0][0], s_T[0][1]), fminf(s_T[0][2], s_T[0][3]));
    const float TB = fminf(fminf(s_T[1][0], s_T[1][1]), fminf(s_T[1][2], s_T[1][3]));
    const float UA = TA + fabsf(TA) * 1e-5f + 5e-4f;
    const float UB = TB + fabsf(TB) * 1e-5f + 5e-4f;

    // ---- Phase 2: filter scan of the quarter; compact indices into LDS ----
    const u64 ltmask = (1ull << lane) - 1ull;
    int cntA = 0, cntB = 0;
#pragma unroll 2
    for (int i = base + lane; i < base + QTR; i += 64) {
        float x0, x1, x2, xs;
        if (PACKED) {
            float4 p = pb[i];
            x0 = p.x; x1 = p.y; x2 = p.z; xs = p.w;
        } else {
            x0 = xb[i * 3 + 0];
            x1 = xb[i * 3 + 1];
            x2 = xb[i * 3 + 2];
            xs = (x0 * x0 + x1 * x1) + x2 * x2;
        }
        float dA = __fmaf_rn(x0, nA0, __fmaf_rn(x1, nA1, __fmaf_rn(x2, nA2, xs)));
        float dB = __fmaf_rn(x0, nB0, __fmaf_rn(x1, nB1, __fmaf_rn(x2, nB2, xs)));
        bool pA = dA <= UA, pB = dB <= UB;
        if (__any(pA || pB)) {
            u64 balA = __ballot(pA);
            if (pA) {
                int pos = cntA + (int)__popcll(balA & ltmask);
                if (pos < HCAP) s_idx[0][q][pos] = (uint32_t)i;
            }
            cntA += (int)__popcll(balA);
            u64 balB = __ballot(pB);
            if (pB) {
                int pos = cntB + (int)__popcll(balB & ltmask);
                if (pos < HCAP) s_idx[1][q][pos] = (uint32_t)i;
            }
            cntB += (int)__popcll(balB);
        }
    }
    if (lane == 0) {
        s_cnt[0][q] = cntA;
        s_cnt[1][q] = cntB;
    }
    __syncthreads();

    // ---- Phase 3: wave 0 -> center A, wave 1 -> center B; waves 2,3 retire ----
    if (q < 2) {
        const int side = q;
        const int cc = cA + side;
        const float c0 = side ? b0 : a0;
        const float c1 = side ? b1 : a1;
        const float c2 = side ? b2 : a2;
        const float csq = side ? csqB : csqA;
        const int c0n = s_cnt[side][0];
        const int c1n = s_cnt[side][1];
        const int c2n = s_cnt[side][2];
        const int c3n = s_cnt[side][3];
        const int p1 = c0n, p2 = c0n + c1n, p3 = c0n + c1n + c2n;
        const int total = p3 + c3n;
        const bool ok = (c0n <= HCAP) & (c1n <= HCAP) & (c2n <= HCAP) &
                        (c3n <= HCAP) & (total <= 4 * 64);

        int res = 0;
        if (ok) {
            // Combined stream -> <= 4 keys/lane -> depth-4 list is exact.
            u64 l0 = ~0ull, l1 = ~0ull, l2 = ~0ull, l3 = ~0ull;
            for (int j = lane; j < total; j += 64) {
                int qq, off;
                if (j < p1)      { qq = 0; off = j; }
                else if (j < p2) { qq = 1; off = j - p1; }
                else if (j < p3) { qq = 2; off = j - p2; }
                else             { qq = 3; off = j - p3; }
                int idx = (int)s_idx[side][qq][off];
                float d2 = point_d2<PACKED>(pb, xb, idx, c0, c1, c2, csq);
                u64 key = ((u64)__float_as_uint(__fsqrt_rn(d2)) << 32) | (u64)(uint32_t)idx;
                bool t;
                t = key < l0; { u64 lo = t ? key : l0, hi = t ? l0 : key; l0 = lo; key = hi; }
                t = key < l1; { u64 lo = t ? key : l1, hi = t ? l1 : key; l1 = lo; key = hi; }
                t = key < l2; { u64 lo = t ? key : l2, hi = t ? l2 : key; l2 = lo; key = hi; }
                t = key < l3; { u64 lo = t ? key : l3, hi = t ? l3 : key; l3 = lo; key = hi; }
            }
            for (int it = 0; it < KNN; ++it) {
                u64 best = wave_min_u64(l0);
                if (it == lane) res = (int)(uint32_t)best;
                if (l0 == best) { l0 = l1; l1 = l2; l2 = l3; l3 = ~0ull; }
            }
        } else {
            res = fallback_scan<PACKED>(pb, xb, c0, c1, c2, csq, lane);
        }

        // out[b][rank][c]
        if (lane < KNN) {
            out[((size_t)b * KNN + lane) * KK + cc] = res;
        }
    }
}

extern "C" void kernel_launch(void* const* d_in, const int* in_sizes, int n_in,
                              void* d_out, int out_size, void* d_ws, size_t ws_size,
                              hipStream_t stream) {
    const float* xyz = (const float*)d_in[0];
    const float* centers = (const float*)d_in[1];
    int* out = (int*)d_out;

    const size_t need = (size_t)BB * NN * 4 * sizeof(float);  // 2 MiB packed points
    const int nblocks = BB * KK / 2;   // 4096 pairs, one pair (4 waves) per block

    if (ws_size >= need) {
        float4* pts = (float4*)d_ws;
        hipLaunchKernelGGL(prep_kernel, dim3((BB * NN + 255) / 256), dim3(256), 0, stream,
                           xyz, pts);
        hipLaunchKernelGGL((knn_kernel<true>), dim3(nblocks), dim3(256), 0, stream,
                           pts, xyz, centers, out);
    } else {
        hipLaunchKernelGGL((knn_kernel<false>), dim3(nblocks), dim3(256), 0, stream,
                           (const float4*)nullptr, xyz, centers, out);
    }
}

// Round 9
// 112.378 us; speedup vs baseline: 1.2090x; 1.2090x over previous
//
#include <hip/hip_runtime.h>
#include <stdint.h>

// Problem constants (from reference setup_inputs)
#define BB    8
#define NN    16384
#define KK    1024
#define KNN   16
#define QTR   (NN / 4)    // each of 4 waves per block owns a quarter of points
#define PILOT 1024        // pilot prefix of each quarter (per-center total 4096)
#define HCAP  96          // survivor slots per (center, quarter); mean ~13

typedef unsigned long long u64;

// Manual 64-bit shuffle-xor (two 32-bit shuffles).
__device__ __forceinline__ u64 shfl_xor_u64(u64 v, int mask) {
    int lo = (int)(uint32_t)v;
    int hi = (int)(uint32_t)(v >> 32);
    lo = __shfl_xor(lo, mask, 64);
    hi = __shfl_xor(hi, mask, 64);
    return ((u64)(uint32_t)hi << 32) | (u64)(uint32_t)lo;
}

// Butterfly min over all 64 lanes; every lane ends with the wave minimum.
__device__ __forceinline__ u64 wave_min_u64(u64 v) {
#pragma unroll
    for (int off = 32; off > 0; off >>= 1) {
        u64 o = shfl_xor_u64(v, off);
        v = o < v ? o : v;
    }
    return v;
}

// Pack (x, y, z, ||x||^2) into aligned float4.
// x_sq per reference: (x0*x0 + x1*x1) + x2*x2, NO fma contraction.
__global__ __launch_bounds__(256) void prep_kernel(const float* __restrict__ xyz,
                                                   float4* __restrict__ pts) {
#pragma clang fp contract(off)
    int i = blockIdx.x * 256 + threadIdx.x;
    if (i < BB * NN) {
        float x0 = xyz[i * 3 + 0];
        float x1 = xyz[i * 3 + 1];
        float x2 = xyz[i * 3 + 2];
        float xsq = (x0 * x0 + x1 * x1) + x2 * x2;
        pts[i] = make_float4(x0, x1, x2, xsq);
    }
}

// EXACT reference d2 (final ranking + fallback): cross = sequential FMA chain
// (einsum -> dot_general -> BLAS microkernel semantics, verified R3); the
// rest plain fp32 ops, no contraction.
template <bool PACKED>
__device__ __forceinline__ float point_d2(const float4* pb, const float* xb, int i,
                                          float c0, float c1, float c2, float csq) {
#pragma clang fp contract(off)
    float x0, x1, x2, xsq;
    if (PACKED) {
        float4 p = pb[i];
        x0 = p.x; x1 = p.y; x2 = p.z; xsq = p.w;
    } else {
        x0 = xb[i * 3 + 0];
        x1 = xb[i * 3 + 1];
        x2 = xb[i * 3 + 2];
        xsq = (x0 * x0 + x1 * x1) + x2 * x2;
    }
    float cross = __fmaf_rn(x2, c2, __fmaf_rn(x1, c1, x0 * c0));
    float d2 = (xsq + csq) - 2.0f * cross;
    return d2 < 0.0f ? 0.0f : d2;   // jnp.maximum(d2, 0)
}

// Cold-path exact fallback (full-N bubble scan), only on cap overflow.
template <bool PACKED>
__device__ __attribute__((noinline)) int fallback_scan(const float4* pb, const float* xb,
                                                       float c0, float c1, float c2,
                                                       float csq, int lane) {
    u64 list[KNN];
#pragma unroll
    for (int j = 0; j < KNN; ++j) list[j] = ~0ull;
    for (int i = lane; i < NN; i += 64) {
        float d2 = point_d2<PACKED>(pb, xb, i, c0, c1, c2, csq);
        float dist = __fsqrt_rn(d2);
        u64 key = ((u64)__float_as_uint(dist) << 32) | (u64)(uint32_t)i;
        if (key < list[KNN - 1]) {
#pragma unroll
            for (int j = 0; j < KNN; ++j) {
                bool lt = key < list[j];
                u64 lo = lt ? key : list[j];
                u64 hi = lt ? list[j] : key;
                list[j] = lo;
                key = hi;
            }
        }
    }
    int res = 0;
    for (int it = 0; it < KNN; ++it) {
        u64 best = wave_min_u64(list[0]);
        if (it == lane) res = (int)(uint32_t)best;
        if (list[0] == best) {
#pragma unroll
            for (int j = 0; j < KNN - 1; ++j) list[j] = list[j + 1];
            list[KNN - 1] = ~0ull;
        }
    }
    return res;
}

// 16th-smallest FLOAT (true float order incl. negatives) of the 64 lane
// values, via full bitonic sort across lanes; lane 15 holds the answer.
__device__ __forceinline__ float sixteenth_smallest(float m, int lane) {
    uint32_t u = __float_as_uint(m);
    uint32_t s = (u & 0x80000000u) ? ~u : (u | 0x80000000u);  // sortable bits
    u64 v = ((u64)s << 32) | (unsigned)lane;                  // unique keys
#pragma unroll
    for (int k = 2; k <= 64; k <<= 1) {
#pragma unroll
        for (int j = k >> 1; j > 0; j >>= 1) {
            u64 o = shfl_xor_u64(v, j);
            bool up = (lane & k) == 0;          // k=64: ascending
            bool takeMin = ((lane & j) == 0) == up;
            u64 mn = v < o ? v : o;
            u64 mx = v < o ? o : v;
            v = takeMin ? mn : mx;
        }
    }
    uint32_t sb = (uint32_t)__shfl((int)(uint32_t)(v >> 32), 15, 64);
    uint32_t ub = (sb & 0x80000000u) ? (sb ^ 0x80000000u) : ~sb;
    return __uint_as_float(ub);
}

// Block = 4 waves owns FOUR consecutive centers; wave q scans quarter q of
// the points for ALL FOUR centers (every loaded point serves 4 evals -> L2
// traffic halves vs R7's C=2; per-eval instr drops via amortized load/loop).
//   Phase 1 (pilot): per-lane min of d' = xs - 2*x.c over the first PILOT pts
//     of this quarter, 4 centers. All waves write minima to LDS; wave q takes
//     the min-of-4-waves per lane for center q (still per-lane minima of real
//     points, now over 4096 pilot pts) and runs ONE bitonic -> T_q (16
//     distinct real points have d' <= T_q => exact 16th-d2 <= T_q+csq+eps).
//   Phase 2 (filter): scan quarter for 4 centers; keep d' <= U = T + |T|*1e-5
//     + 5e-4 (margin family verified R5-R8). Ballot-compact indices into LDS.
//   Phase 3: wave q reranks center q over the 4 quarter buffers (total <= 256
//     -> <= 4 keys/lane, depth-4 exact); verified (sqrt_rn-dist, idx) key.
template <bool PACKED>
__global__ __launch_bounds__(256, 8) void knn_kernel(const float4* __restrict__ pts,
                                                     const float* __restrict__ xyz,
                                                     const float* __restrict__ centers,
                                                     int* __restrict__ out) {
#pragma clang fp contract(off)
    const int q = (int)(threadIdx.x >> 6);    // wave in block = quarter = owned center
    const int lane = (int)(threadIdx.x & 63);
    const int cbase = (int)blockIdx.x * 4;    // global center id of center 0
    const int b = cbase >> 10;                // batch

    __shared__ float    s_min[4][256];        // [center][srcwave*64+lane] 4 KB
    __shared__ float    s_T[4];               // [center]
    __shared__ int      s_cnt[4][4];          // [center][quarter]
    __shared__ uint32_t s_idx[4][4][HCAP];    // [center][quarter][slot] 6 KB

    // folded center consts: n = -2*c (exact)
    const float n00 = -2.0f * centers[(cbase + 0) * 3 + 0];
    const float n01 = -2.0f * centers[(cbase + 0) * 3 + 1];
    const float n02 = -2.0f * centers[(cbase + 0) * 3 + 2];
    const float n10 = -2.0f * centers[(cbase + 1) * 3 + 0];
    const float n11 = -2.0f * centers[(cbase + 1) * 3 + 1];
    const float n12 = -2.0f * centers[(cbase + 1) * 3 + 2];
    const float n20 = -2.0f * centers[(cbase + 2) * 3 + 0];
    const float n21 = -2.0f * centers[(cbase + 2) * 3 + 1];
    const float n22 = -2.0f * centers[(cbase + 2) * 3 + 2];
    const float n30 = -2.0f * centers[(cbase + 3) * 3 + 0];
    const float n31 = -2.0f * centers[(cbase + 3) * 3 + 1];
    const float n32 = -2.0f * centers[(cbase + 3) * 3 + 2];

    const float4* pb = pts + (size_t)b * NN;
    const float* xb = xyz + (size_t)b * NN * 3;
    const int base = q * QTR;

    // ---- Phase 1: pilot minima over first PILOT pts of this quarter ----
    float m0 = __builtin_inff(), m1 = m0, m2 = m0, m3 = m0;
#pragma unroll 4
    for (int i = base + lane; i < base + PILOT; i += 64) {
        float x0, x1, x2, xs;
        if (PACKED) {
            float4 p = pb[i];
            x0 = p.x; x1 = p.y; x2 = p.z; xs = p.w;
        } else {
            x0 = xb[i * 3 + 0];
            x1 = xb[i * 3 + 1];
            x2 = xb[i * 3 + 2];
            xs = (x0 * x0 + x1 * x1) + x2 * x2;
        }
        float d0 = __fmaf_rn(x0, n00, __fmaf_rn(x1, n01, __fmaf_rn(x2, n02, xs)));
        float d1 = __fmaf_rn(x0, n10, __fmaf_rn(x1, n11, __fmaf_rn(x2, n12, xs)));
        float d2 = __fmaf_rn(x0, n20, __fmaf_rn(x1, n21, __fmaf_rn(x2, n22, xs)));
        float d3 = __fmaf_rn(x0, n30, __fmaf_rn(x1, n31, __fmaf_rn(x2, n32, xs)));
        m0 = d0 < m0 ? d0 : m0;
        m1 = d1 < m1 ? d1 : m1;
        m2 = d2 < m2 ? d2 : m2;
        m3 = d3 < m3 ? d3 : m3;
    }
    s_min[0][q * 64 + lane] = m0;
    s_min[1][q * 64 + lane] = m1;
    s_min[2][q * 64 + lane] = m2;
    s_min[3][q * 64 + lane] = m3;
    __syncthreads();
    {
        // wave q: per-lane min across the 4 source waves for center q, then
        // one bitonic. Each min-of-4 is still a single real point's d'.
        float v = fminf(fminf(s_min[q][lane], s_min[q][64 + lane]),
                        fminf(s_min[q][128 + lane], s_min[q][192 + lane]));
        float t = sixteenth_smallest(v, lane);
        if (lane == 0) s_T[q] = t;
    }
    __syncthreads();
    const float T0 = s_T[0], T1 = s_T[1], T2 = s_T[2], T3 = s_T[3];
    const float U0 = T0 + fabsf(T0) * 1e-5f + 5e-4f;
    const float U1 = T1 + fabsf(T1) * 1e-5f + 5e-4f;
    const float U2 = T2 + fabsf(T2) * 1e-5f + 5e-4f;
    const float U3 = T3 + fabsf(T3) * 1e-5f + 5e-4f;

    // ---- Phase 2: filter scan of the quarter for all 4 centers ----
    const u64 ltmask = (1ull << lane) - 1ull;
    int c0n = 0, c1n = 0, c2n = 0, c3n = 0;
#pragma unroll 2
    for (int i = base + lane; i < base + QTR; i += 64) {
        float x0, x1, x2, xs;
        if (PACKED) {
            float4 p = pb[i];
            x0 = p.x; x1 = p.y; x2 = p.z; xs = p.w;
        } else {
            x0 = xb[i * 3 + 0];
            x1 = xb[i * 3 + 1];
            x2 = xb[i * 3 + 2];
            xs = (x0 * x0 + x1 * x1) + x2 * x2;
        }
        float d0 = __fmaf_rn(x0, n00, __fmaf_rn(x1, n01, __fmaf_rn(x2, n02, xs)));
        float d1 = __fmaf_rn(x0, n10, __fmaf_rn(x1, n11, __fmaf_rn(x2, n12, xs)));
        float d2 = __fmaf_rn(x0, n20, __fmaf_rn(x1, n21, __fmaf_rn(x2, n22, xs)));
        float d3 = __fmaf_rn(x0, n30, __fmaf_rn(x1, n31, __fmaf_rn(x2, n32, xs)));
        bool p0 = d0 <= U0, p1 = d1 <= U1, p2 = d2 <= U2, p3 = d3 <= U3;
        u64 bal;
        bal = __ballot(p0);
        if (bal) {
            if (p0) {
                int pos = c0n + (int)__popcll(bal & ltmask);
                if (pos < HCAP) s_idx[0][q][pos] = (uint32_t)i;
            }
            c0n += (int)__popcll(bal);
        }
        bal = __ballot(p1);
        if (bal) {
            if (p1) {
                int pos = c1n + (int)__popcll(bal & ltmask);
                if (pos < HCAP) s_idx[1][q][pos] = (uint32_t)i;
            }
            c1n += (int)__popcll(bal);
        }
        bal = __ballot(p2);
        if (bal) {
            if (p2) {
                int pos = c2n + (int)__popcll(bal & ltmask);
                if (pos < HCAP) s_idx[2][q][pos] = (uint32_t)i;
            }
            c2n += (int)__popcll(bal);
        }
        bal = __ballot(p3);
        if (bal) {
            if (p3) {
                int pos = c3n + (int)__popcll(bal & ltmask);
                if (pos < HCAP) s_idx[3][q][pos] = (uint32_t)i;
            }
            c3n += (int)__popcll(bal);
        }
    }
    if (lane == 0) {
        s_cnt[0][q] = c0n;
        s_cnt[1][q] = c1n;
        s_cnt[2][q] = c2n;
        s_cnt[3][q] = c3n;
    }
    __syncthreads();

    // ---- Phase 3: wave q reranks center q exactly (no idle waves) ----
    const int cc = cbase + q;
    const float c0 = centers[cc * 3 + 0];   // uniform s_loads, L2-hot
    const float c1 = centers[cc * 3 + 1];
    const float c2 = centers[cc * 3 + 2];
    const float csq = (c0 * c0 + c1 * c1) + c2 * c2;  // exact non-FMA reduce
    const int k0 = s_cnt[q][0], k1 = s_cnt[q][1], k2 = s_cnt[q][2], k3 = s_cnt[q][3];
    const int p1o = k0, p2o = k0 + k1, p3o = k0 + k1 + k2;
    const int total = p3o + k3;
    const bool ok = (k0 <= HCAP) & (k1 <= HCAP) & (k2 <= HCAP) & (k3 <= HCAP) &
                    (total <= 4 * 64);

    int res = 0;
    if (ok) {
        // Combined stream -> <= 4 keys/lane -> depth-4 list is exact.
        u64 l0 = ~0ull, l1 = ~0ull, l2 = ~0ull, l3 = ~0ull;
        for (int j = lane; j < total; j += 64) {
            int qq, off;
            if (j < p1o)      { qq = 0; off = j; }
            else if (j < p2o) { qq = 1; off = j - p1o; }
            else if (j < p3o) { qq = 2; off = j - p2o; }
            else              { qq = 3; off = j - p3o; }
            int idx = (int)s_idx[q][qq][off];
            float d2 = point_d2<PACKED>(pb, xb, idx, c0, c1, c2, csq);
            u64 key = ((u64)__float_as_uint(__fsqrt_rn(d2)) << 32) | (u64)(uint32_t)idx;
            bool t;
            t = key < l0; { u64 lo = t ? key : l0, hi = t ? l0 : key; l0 = lo; key = hi; }
            t = key < l1; { u64 lo = t ? key : l1, hi = t ? l1 : key; l1 = lo; key = hi; }
            t = key < l2; { u64 lo = t ? key : l2, hi = t ? l2 : key; l2 = lo; key = hi; }
            t = key < l3; { u64 lo = t ? key : l3, hi = t ? l3 : key; l3 = lo; key = hi; }
        }
        for (int it = 0; it < KNN; ++it) {
            u64 best = wave_min_u64(l0);
            if (it == lane) res = (int)(uint32_t)best;
            if (l0 == best) { l0 = l1; l1 = l2; l2 = l3; l3 = ~0ull; }
        }
    } else {
        res = fallback_scan<PACKED>(pb, xb, c0, c1, c2, csq, lane);
    }

    // out[b][rank][c_in_batch]
    if (lane < KNN) {
        out[((size_t)b * KNN + lane) * KK + (cc & 1023)] = res;
    }
}

extern "C" void kernel_launch(void* const* d_in, const int* in_sizes, int n_in,
                              void* d_out, int out_size, void* d_ws, size_t ws_size,
                              hipStream_t stream) {
    const float* xyz = (const float*)d_in[0];
    const float* centers = (const float*)d_in[1];
    int* out = (int*)d_out;

    const size_t need = (size_t)BB * NN * 4 * sizeof(float);  // 2 MiB packed points
    const int nblocks = BB * KK / 4;   // 2048 blocks x 4 waves = 8192 waves (8/SIMD)

    if (ws_size >= need) {
        float4* pts = (float4*)d_ws;
        hipLaunchKernelGGL(prep_kernel, dim3((BB * NN + 255) / 256), dim3(256), 0, stream,
                           xyz, pts);
        hipLaunchKernelGGL((knn_kernel<true>), dim3(nblocks), dim3(256), 0, stream,
                           pts, xyz, centers, out);
    } else {
        hipLaunchKernelGGL((knn_kernel<false>), dim3(nblocks), dim3(256), 0, stream,
                           (const float4*)nullptr, xyz, centers, out);
    }
}

// Round 10
// 107.901 us; speedup vs baseline: 1.2592x; 1.0415x over previous
//
#include <hip/hip_runtime.h>
#include <stdint.h>

// Problem constants (from reference setup_inputs)
#define BB    8
#define NN    16384
#define KK    1024
#define KNN   16
#define QTR   (NN / 4)    // each of 4 waves per block owns a quarter of points
#define PILOT 1024        // pilot prefix of each quarter (per-center total 4096)
#define HCAP  96          // survivor slots per (center, quarter); mean ~19

typedef unsigned long long u64;

// Manual 64-bit shuffle-xor (two 32-bit shuffles).
__device__ __forceinline__ u64 shfl_xor_u64(u64 v, int mask) {
    int lo = (int)(uint32_t)v;
    int hi = (int)(uint32_t)(v >> 32);
    lo = __shfl_xor(lo, mask, 64);
    hi = __shfl_xor(hi, mask, 64);
    return ((u64)(uint32_t)hi << 32) | (u64)(uint32_t)lo;
}

// Butterfly min over all 64 lanes; every lane ends with the wave minimum.
__device__ __forceinline__ u64 wave_min_u64(u64 v) {
#pragma unroll
    for (int off = 32; off > 0; off >>= 1) {
        u64 o = shfl_xor_u64(v, off);
        v = o < v ? o : v;
    }
    return v;
}

// Pack (x, y, z, ||x||^2) into aligned float4.
// x_sq per reference: (x0*x0 + x1*x1) + x2*x2, NO fma contraction.
__global__ __launch_bounds__(256) void prep_kernel(const float* __restrict__ xyz,
                                                   float4* __restrict__ pts) {
#pragma clang fp contract(off)
    int i = blockIdx.x * 256 + threadIdx.x;
    if (i < BB * NN) {
        float x0 = xyz[i * 3 + 0];
        float x1 = xyz[i * 3 + 1];
        float x2 = xyz[i * 3 + 2];
        float xsq = (x0 * x0 + x1 * x1) + x2 * x2;
        pts[i] = make_float4(x0, x1, x2, xsq);
    }
}

// EXACT reference d2 (final ranking + fallback): cross = sequential FMA chain
// (einsum -> dot_general -> BLAS microkernel semantics, verified R3); the
// rest plain fp32 ops, no contraction.
template <bool PACKED>
__device__ __forceinline__ float point_d2(const float4* pb, const float* xb, int i,
                                          float c0, float c1, float c2, float csq) {
#pragma clang fp contract(off)
    float x0, x1, x2, xsq;
    if (PACKED) {
        float4 p = pb[i];
        x0 = p.x; x1 = p.y; x2 = p.z; xsq = p.w;
    } else {
        x0 = xb[i * 3 + 0];
        x1 = xb[i * 3 + 1];
        x2 = xb[i * 3 + 2];
        xsq = (x0 * x0 + x1 * x1) + x2 * x2;
    }
    float cross = __fmaf_rn(x2, c2, __fmaf_rn(x1, c1, x0 * c0));
    float d2 = (xsq + csq) - 2.0f * cross;
    return d2 < 0.0f ? 0.0f : d2;   // jnp.maximum(d2, 0)
}

// Cold-path exact fallback (full-N bubble scan), only on cap overflow.
template <bool PACKED>
__device__ __attribute__((noinline)) int fallback_scan(const float4* pb, const float* xb,
                                                       float c0, float c1, float c2,
                                                       float csq, int lane) {
    u64 list[KNN];
#pragma unroll
    for (int j = 0; j < KNN; ++j) list[j] = ~0ull;
    for (int i = lane; i < NN; i += 64) {
        float d2 = point_d2<PACKED>(pb, xb, i, c0, c1, c2, csq);
        float dist = __fsqrt_rn(d2);
        u64 key = ((u64)__float_as_uint(dist) << 32) | (u64)(uint32_t)i;
        if (key < list[KNN - 1]) {
#pragma unroll
            for (int j = 0; j < KNN; ++j) {
                bool lt = key < list[j];
                u64 lo = lt ? key : list[j];
                u64 hi = lt ? list[j] : key;
                list[j] = lo;
                key = hi;
            }
        }
    }
    int res = 0;
    for (int it = 0; it < KNN; ++it) {
        u64 best = wave_min_u64(list[0]);
        if (it == lane) res = (int)(uint32_t)best;
        if (list[0] == best) {
#pragma unroll
            for (int j = 0; j < KNN - 1; ++j) list[j] = list[j + 1];
            list[KNN - 1] = ~0ull;
        }
    }
    return res;
}

// 16th-smallest FLOAT (true float order incl. negatives) of the 64 lane
// values, via full bitonic sort across lanes; lane 15 holds the answer.
__device__ __forceinline__ float sixteenth_smallest(float m, int lane) {
    uint32_t u = __float_as_uint(m);
    uint32_t s = (u & 0x80000000u) ? ~u : (u | 0x80000000u);  // sortable bits
    u64 v = ((u64)s << 32) | (unsigned)lane;                  // unique keys
#pragma unroll
    for (int k = 2; k <= 64; k <<= 1) {
#pragma unroll
        for (int j = k >> 1; j > 0; j >>= 1) {
            u64 o = shfl_xor_u64(v, j);
            bool up = (lane & k) == 0;          // k=64: ascending
            bool takeMin = ((lane & j) == 0) == up;
            u64 mn = v < o ? v : o;
            u64 mx = v < o ? o : v;
            v = takeMin ? mn : mx;
        }
    }
    uint32_t sb = (uint32_t)__shfl((int)(uint32_t)(v >> 32), 15, 64);
    uint32_t ub = (sb & 0x80000000u) ? (sb ^ 0x80000000u) : ~sb;
    return __uint_as_float(ub);
}

// Block = 4 waves owns FOUR consecutive centers; wave q scans quarter q for
// all four centers. R10 change (one variable): phase-2 compaction switches
// from ballot+prefix (measured ~2K VALU/wave of bookkeeping, ~30% of the
// kernel) to DIVERGENT LDS-ATOMIC compaction — survivors are rare (~19 per
// wave-center over 64 iters), so the common-case per center-iteration cost
// drops to one v_cmp + an execz-skipped branch. Survivor order in the buffer
// becomes arbitrary, which is harmless: phase 3 exactly reranks survivors by
// the verified (sqrt_rn-dist bits, idx) u64 key. s_cnt[c][q] is exclusive to
// wave q -> no cross-wave atomic contention.
template <bool PACKED>
__global__ __launch_bounds__(256, 8) void knn_kernel(const float4* __restrict__ pts,
                                                     const float* __restrict__ xyz,
                                                     const float* __restrict__ centers,
                                                     int* __restrict__ out) {
#pragma clang fp contract(off)
    const int q = (int)(threadIdx.x >> 6);    // wave in block = quarter = owned center
    const int lane = (int)(threadIdx.x & 63);
    const int cbase = (int)blockIdx.x * 4;    // global center id of center 0
    const int b = cbase >> 10;                // batch

    __shared__ float    s_min[4][256];        // [center][srcwave*64+lane] 4 KB
    __shared__ float    s_T[4];               // [center]
    __shared__ int      s_cnt[4][4];          // [center][quarter]
    __shared__ uint32_t s_idx[4][4][HCAP];    // [center][quarter][slot] 6 KB

    // folded center consts: n = -2*c (exact)
    const float n00 = -2.0f * centers[(cbase + 0) * 3 + 0];
    const float n01 = -2.0f * centers[(cbase + 0) * 3 + 1];
    const float n02 = -2.0f * centers[(cbase + 0) * 3 + 2];
    const float n10 = -2.0f * centers[(cbase + 1) * 3 + 0];
    const float n11 = -2.0f * centers[(cbase + 1) * 3 + 1];
    const float n12 = -2.0f * centers[(cbase + 1) * 3 + 2];
    const float n20 = -2.0f * centers[(cbase + 2) * 3 + 0];
    const float n21 = -2.0f * centers[(cbase + 2) * 3 + 1];
    const float n22 = -2.0f * centers[(cbase + 2) * 3 + 2];
    const float n30 = -2.0f * centers[(cbase + 3) * 3 + 0];
    const float n31 = -2.0f * centers[(cbase + 3) * 3 + 1];
    const float n32 = -2.0f * centers[(cbase + 3) * 3 + 2];

    const float4* pb = pts + (size_t)b * NN;
    const float* xb = xyz + (size_t)b * NN * 3;
    const int base = q * QTR;

    // ---- Phase 1: pilot minima over first PILOT pts of this quarter ----
    float m0 = __builtin_inff(), m1 = m0, m2 = m0, m3 = m0;
#pragma unroll 4
    for (int i = base + lane; i < base + PILOT; i += 64) {
        float x0, x1, x2, xs;
        if (PACKED) {
            float4 p = pb[i];
            x0 = p.x; x1 = p.y; x2 = p.z; xs = p.w;
        } else {
            x0 = xb[i * 3 + 0];
            x1 = xb[i * 3 + 1];
            x2 = xb[i * 3 + 2];
            xs = (x0 * x0 + x1 * x1) + x2 * x2;
        }
        float d0 = __fmaf_rn(x0, n00, __fmaf_rn(x1, n01, __fmaf_rn(x2, n02, xs)));
        float d1 = __fmaf_rn(x0, n10, __fmaf_rn(x1, n11, __fmaf_rn(x2, n12, xs)));
        float d2 = __fmaf_rn(x0, n20, __fmaf_rn(x1, n21, __fmaf_rn(x2, n22, xs)));
        float d3 = __fmaf_rn(x0, n30, __fmaf_rn(x1, n31, __fmaf_rn(x2, n32, xs)));
        m0 = d0 < m0 ? d0 : m0;
        m1 = d1 < m1 ? d1 : m1;
        m2 = d2 < m2 ? d2 : m2;
        m3 = d3 < m3 ? d3 : m3;
    }
    s_min[0][q * 64 + lane] = m0;
    s_min[1][q * 64 + lane] = m1;
    s_min[2][q * 64 + lane] = m2;
    s_min[3][q * 64 + lane] = m3;
    // zero the survivor counters while we're pre-barrier anyway
    if (threadIdx.x < 16) s_cnt[threadIdx.x >> 2][threadIdx.x & 3] = 0;
    __syncthreads();
    {
        // wave q: per-lane min across the 4 source waves for center q, then
        // one bitonic. Each min-of-4 is still a single real point's d'.
        float v = fminf(fminf(s_min[q][lane], s_min[q][64 + lane]),
                        fminf(s_min[q][128 + lane], s_min[q][192 + lane]));
        float t = sixteenth_smallest(v, lane);
        if (lane == 0) s_T[q] = t;
    }
    __syncthreads();
    const float T0 = s_T[0], T1 = s_T[1], T2 = s_T[2], T3 = s_T[3];
    const float U0 = T0 + fabsf(T0) * 1e-5f + 5e-4f;
    const float U1 = T1 + fabsf(T1) * 1e-5f + 5e-4f;
    const float U2 = T2 + fabsf(T2) * 1e-5f + 5e-4f;
    const float U3 = T3 + fabsf(T3) * 1e-5f + 5e-4f;

    // ---- Phase 2: filter scan; divergent atomic compaction into LDS ----
#pragma unroll 2
    for (int i = base + lane; i < base + QTR; i += 64) {
        float x0, x1, x2, xs;
        if (PACKED) {
            float4 p = pb[i];
            x0 = p.x; x1 = p.y; x2 = p.z; xs = p.w;
        } else {
            x0 = xb[i * 3 + 0];
            x1 = xb[i * 3 + 1];
            x2 = xb[i * 3 + 2];
            xs = (x0 * x0 + x1 * x1) + x2 * x2;
        }
        float d0 = __fmaf_rn(x0, n00, __fmaf_rn(x1, n01, __fmaf_rn(x2, n02, xs)));
        float d1 = __fmaf_rn(x0, n10, __fmaf_rn(x1, n11, __fmaf_rn(x2, n12, xs)));
        float d2 = __fmaf_rn(x0, n20, __fmaf_rn(x1, n21, __fmaf_rn(x2, n22, xs)));
        float d3 = __fmaf_rn(x0, n30, __fmaf_rn(x1, n31, __fmaf_rn(x2, n32, xs)));
        if (d0 <= U0) {
            int pos = atomicAdd(&s_cnt[0][q], 1);
            if (pos < HCAP) s_idx[0][q][pos] = (uint32_t)i;
        }
        if (d1 <= U1) {
            int pos = atomicAdd(&s_cnt[1][q], 1);
            if (pos < HCAP) s_idx[1][q][pos] = (uint32_t)i;
        }
        if (d2 <= U2) {
            int pos = atomicAdd(&s_cnt[2][q], 1);
            if (pos < HCAP) s_idx[2][q][pos] = (uint32_t)i;
        }
        if (d3 <= U3) {
            int pos = atomicAdd(&s_cnt[3][q], 1);
            if (pos < HCAP) s_idx[3][q][pos] = (uint32_t)i;
        }
    }
    __syncthreads();

    // ---- Phase 3: wave q reranks center q exactly (no idle waves) ----
    const int cc = cbase + q;
    const float c0 = centers[cc * 3 + 0];   // uniform s_loads, L2-hot
    const float c1 = centers[cc * 3 + 1];
    const float c2 = centers[cc * 3 + 2];
    const float csq = (c0 * c0 + c1 * c1) + c2 * c2;  // exact non-FMA reduce
    const int k0 = s_cnt[q][0], k1 = s_cnt[q][1], k2 = s_cnt[q][2], k3 = s_cnt[q][3];
    const int p1o = k0, p2o = k0 + k1, p3o = k0 + k1 + k2;
    const int total = p3o + k3;
    const bool ok = (k0 <= HCAP) & (k1 <= HCAP) & (k2 <= HCAP) & (k3 <= HCAP) &
                    (total <= 4 * 64);

    int res = 0;
    if (ok) {
        // Combined stream -> <= 4 keys/lane -> depth-4 list is exact.
        u64 l0 = ~0ull, l1 = ~0ull, l2 = ~0ull, l3 = ~0ull;
        for (int j = lane; j < total; j += 64) {
            int qq, off;
            if (j < p1o)      { qq = 0; off = j; }
            else if (j < p2o) { qq = 1; off = j - p1o; }
            else if (j < p3o) { qq = 2; off = j - p2o; }
            else              { qq = 3; off = j - p3o; }
            int idx = (int)s_idx[q][qq][off];
            float d2 = point_d2<PACKED>(pb, xb, idx, c0, c1, c2, csq);
            u64 key = ((u64)__float_as_uint(__fsqrt_rn(d2)) << 32) | (u64)(uint32_t)idx;
            bool t;
            t = key < l0; { u64 lo = t ? key : l0, hi = t ? l0 : key; l0 = lo; key = hi; }
            t = key < l1; { u64 lo = t ? key : l1, hi = t ? l1 : key; l1 = lo; key = hi; }
            t = key < l2; { u64 lo = t ? key : l2, hi = t ? l2 : key; l2 = lo; key = hi; }
            t = key < l3; { u64 lo = t ? key : l3, hi = t ? l3 : key; l3 = lo; key = hi; }
        }
        for (int it = 0; it < KNN; ++it) {
            u64 best = wave_min_u64(l0);
            if (it == lane) res = (int)(uint32_t)best;
            if (l0 == best) { l0 = l1; l1 = l2; l2 = l3; l3 = ~0ull; }
        }
    } else {
        res = fallback_scan<PACKED>(pb, xb, c0, c1, c2, csq, lane);
    }

    // out[b][rank][c_in_batch]
    if (lane < KNN) {
        out[((size_t)b * KNN + lane) * KK + (cc & 1023)] = res;
    }
}

extern "C" void kernel_launch(void* const* d_in, const int* in_sizes, int n_in,
                              void* d_out, int out_size, void* d_ws, size_t ws_size,
                              hipStream_t stream) {
    const float* xyz = (const float*)d_in[0];
    const float* centers = (const float*)d_in[1];
    int* out = (int*)d_out;

    const size_t need = (size_t)BB * NN * 4 * sizeof(float);  // 2 MiB packed points
    const int nblocks = BB * KK / 4;   // 2048 blocks x 4 waves = 8192 waves (8/SIMD)

    if (ws_size >= need) {
        float4* pts = (float4*)d_ws;
        hipLaunchKernelGGL(prep_kernel, dim3((BB * NN + 255) / 256), dim3(256), 0, stream,
                           xyz, pts);
        hipLaunchKernelGGL((knn_kernel<true>), dim3(nblocks), dim3(256), 0, stream,
                           pts, xyz, centers, out);
    } else {
        hipLaunchKernelGGL((knn_kernel<false>), dim3(nblocks), dim3(256), 0, stream,
                           (const float4*)nullptr, xyz, centers, out);
    }
}

// Round 11
// 98.458 us; speedup vs baseline: 1.3799x; 1.0959x over previous
//
#include <hip/hip_runtime.h>
#include <stdint.h>

// Problem constants (from reference setup_inputs)
#define BB    8
#define NN    16384
#define KK    1024
#define KNN   16
#define QTR   (NN / 4)    // each of 4 waves per block owns a quarter of points
#define QGRP  (QTR / 4)   // float4-groups (4 pts) per quarter = 1024
#define PGRP  256         // pilot groups per quarter (= 1024 pts, as R9/R10)
#define HCAP  96          // survivor slots per (center, quarter); mean ~19

typedef unsigned long long u64;

// Manual 64-bit shuffle-xor (two 32-bit shuffles).
__device__ __forceinline__ u64 shfl_xor_u64(u64 v, int mask) {
    int lo = (int)(uint32_t)v;
    int hi = (int)(uint32_t)(v >> 32);
    lo = __shfl_xor(lo, mask, 64);
    hi = __shfl_xor(hi, mask, 64);
    return ((u64)(uint32_t)hi << 32) | (u64)(uint32_t)lo;
}

// Butterfly min over all 64 lanes; every lane ends with the wave minimum.
__device__ __forceinline__ u64 wave_min_u64(u64 v) {
#pragma unroll
    for (int off = 32; off > 0; off >>= 1) {
        u64 o = shfl_xor_u64(v, off);
        v = o < v ? o : v;
    }
    return v;
}

// EXACT reference d2 (final ranking + fallback): cross = sequential FMA chain
// (einsum -> dot_general -> BLAS microkernel semantics, verified R3);
// x_sq/c_sq plain non-FMA reduce, elementwise ops left-to-right.
__device__ __forceinline__ float point_d2(const float* xb, int i,
                                          float c0, float c1, float c2, float csq) {
#pragma clang fp contract(off)
    float x0 = xb[i * 3 + 0];
    float x1 = xb[i * 3 + 1];
    float x2 = xb[i * 3 + 2];
    float xsq = (x0 * x0 + x1 * x1) + x2 * x2;
    float cross = __fmaf_rn(x2, c2, __fmaf_rn(x1, c1, x0 * c0));
    float d2 = (xsq + csq) - 2.0f * cross;
    return d2 < 0.0f ? 0.0f : d2;   // jnp.maximum(d2, 0)
}

// Cold-path exact fallback (full-N bubble scan), only on cap overflow.
__device__ __attribute__((noinline)) int fallback_scan(const float* xb,
                                                       float c0, float c1, float c2,
                                                       float csq, int lane) {
    u64 list[KNN];
#pragma unroll
    for (int j = 0; j < KNN; ++j) list[j] = ~0ull;
    for (int i = lane; i < NN; i += 64) {
        float d2 = point_d2(xb, i, c0, c1, c2, csq);
        float dist = __fsqrt_rn(d2);
        u64 key = ((u64)__float_as_uint(dist) << 32) | (u64)(uint32_t)i;
        if (key < list[KNN - 1]) {
#pragma unroll
            for (int j = 0; j < KNN; ++j) {
                bool lt = key < list[j];
                u64 lo = lt ? key : list[j];
                u64 hi = lt ? list[j] : key;
                list[j] = lo;
                key = hi;
            }
        }
    }
    int res = 0;
    for (int it = 0; it < KNN; ++it) {
        u64 best = wave_min_u64(list[0]);
        if (it == lane) res = (int)(uint32_t)best;
        if (list[0] == best) {
#pragma unroll
            for (int j = 0; j < KNN - 1; ++j) list[j] = list[j + 1];
            list[KNN - 1] = ~0ull;
        }
    }
    return res;
}

// 16th-smallest FLOAT (true float order incl. negatives) of the 64 lane
// values, via full bitonic sort across lanes; lane 15 holds the answer.
__device__ __forceinline__ float sixteenth_smallest(float m, int lane) {
    uint32_t u = __float_as_uint(m);
    uint32_t s = (u & 0x80000000u) ? ~u : (u | 0x80000000u);  // sortable bits
    u64 v = ((u64)s << 32) | (unsigned)lane;                  // unique keys
#pragma unroll
    for (int k = 2; k <= 64; k <<= 1) {
#pragma unroll
        for (int j = k >> 1; j > 0; j >>= 1) {
            u64 o = shfl_xor_u64(v, j);
            bool up = (lane & k) == 0;          // k=64: ascending
            bool takeMin = ((lane & j) == 0) == up;
            u64 mn = v < o ? v : o;
            u64 mx = v < o ? o : v;
            v = takeMin ? mn : mx;
        }
    }
    uint32_t sb = (uint32_t)__shfl((int)(uint32_t)(v >> 32), 15, 64);
    uint32_t ub = (sb & 0x80000000u) ? (sb ^ 0x80000000u) : ~sb;
    return __uint_as_float(ub);
}

// Unpack a group of 4 points (3 float4 = 48 B) + their exact xs.
__device__ __forceinline__ void load_group(const float4* x4, int g,
                                           float (&px)[4], float (&py)[4],
                                           float (&pz)[4], float (&xs)[4]) {
#pragma clang fp contract(off)
    float4 f0 = x4[g * 3 + 0];
    float4 f1 = x4[g * 3 + 1];
    float4 f2 = x4[g * 3 + 2];
    px[0] = f0.x; py[0] = f0.y; pz[0] = f0.z;
    px[1] = f0.w; py[1] = f1.x; pz[1] = f1.y;
    px[2] = f1.z; py[2] = f1.w; pz[2] = f2.x;
    px[3] = f2.y; py[3] = f2.z; pz[3] = f2.w;
#pragma unroll
    for (int k = 0; k < 4; ++k)
        xs[k] = (px[k] * px[k] + py[k] * py[k]) + pz[k] * pz[k];  // non-FMA, exact
}

// Block = 4 waves owns FOUR consecutive centers; wave q scans quarter q for
// all four centers. R11 change: NO prep kernel — each lane owns 4 consecutive
// points per superiter, loaded as 3x dwordx4 (48 B) straight from xyz, xs
// computed inline (reference-exact). 25% fewer VMEM ops and L2 bytes than the
// float4-packed path, minus one kernel launch.
//   Phase 1 (pilot): per-lane min of d' = xs - 2*x.c over the first PGRP
//     groups of the quarter; min-of-4-waves via LDS, one bitonic -> T.
//   Phase 2 (filter): d' <= U = T + |T|*1e-5 + 5e-4 (verified R5-R10);
//     divergent LDS-atomic compaction (verified R10).
//   Phase 3: wave q reranks center q (total <= 256 -> <= 4 keys/lane exact)
//     by the verified (sqrt_rn-dist bits, idx) u64 key.
__global__ __launch_bounds__(256, 8) void knn_kernel(const float* __restrict__ xyz,
                                                     const float* __restrict__ centers,
                                                     int* __restrict__ out) {
#pragma clang fp contract(off)
    const int q = (int)(threadIdx.x >> 6);    // wave in block = quarter = owned center
    const int lane = (int)(threadIdx.x & 63);
    const int cbase = (int)blockIdx.x * 4;    // global center id of center 0
    const int b = cbase >> 10;                // batch

    __shared__ float    s_min[4][256];        // [center][srcwave*64+lane] 4 KB
    __shared__ float    s_T[4];               // [center]
    __shared__ int      s_cnt[4][4];          // [center][quarter]
    __shared__ uint32_t s_idx[4][4][HCAP];    // [center][quarter][slot] 6 KB

    // folded center consts: n = -2*c (exact)
    const float n0[3] = { -2.0f * centers[(cbase + 0) * 3 + 0],
                          -2.0f * centers[(cbase + 0) * 3 + 1],
                          -2.0f * centers[(cbase + 0) * 3 + 2] };
    const float n1[3] = { -2.0f * centers[(cbase + 1) * 3 + 0],
                          -2.0f * centers[(cbase + 1) * 3 + 1],
                          -2.0f * centers[(cbase + 1) * 3 + 2] };
    const float n2[3] = { -2.0f * centers[(cbase + 2) * 3 + 0],
                          -2.0f * centers[(cbase + 2) * 3 + 1],
                          -2.0f * centers[(cbase + 2) * 3 + 2] };
    const float n3[3] = { -2.0f * centers[(cbase + 3) * 3 + 0],
                          -2.0f * centers[(cbase + 3) * 3 + 1],
                          -2.0f * centers[(cbase + 3) * 3 + 2] };

    const float* xb = xyz + (size_t)b * NN * 3;
    const float4* x4 = (const float4*)xb;     // batch base is 16B-aligned
    const int gbase = q * QGRP;               // first group of this quarter

    // ---- Phase 1: pilot minima over first PGRP groups of this quarter ----
    float m0 = __builtin_inff(), m1 = m0, m2 = m0, m3 = m0;
#pragma unroll 2
    for (int s = 0; s < PGRP / 64; ++s) {
        int g = gbase + s * 64 + lane;
        float px[4], py[4], pz[4], xs[4];
        load_group(x4, g, px, py, pz, xs);
#pragma unroll
        for (int k = 0; k < 4; ++k) {
            float d0 = __fmaf_rn(px[k], n0[0], __fmaf_rn(py[k], n0[1], __fmaf_rn(pz[k], n0[2], xs[k])));
            float d1 = __fmaf_rn(px[k], n1[0], __fmaf_rn(py[k], n1[1], __fmaf_rn(pz[k], n1[2], xs[k])));
            float d2 = __fmaf_rn(px[k], n2[0], __fmaf_rn(py[k], n2[1], __fmaf_rn(pz[k], n2[2], xs[k])));
            float d3 = __fmaf_rn(px[k], n3[0], __fmaf_rn(py[k], n3[1], __fmaf_rn(pz[k], n3[2], xs[k])));
            m0 = d0 < m0 ? d0 : m0;
            m1 = d1 < m1 ? d1 : m1;
            m2 = d2 < m2 ? d2 : m2;
            m3 = d3 < m3 ? d3 : m3;
        }
    }
    s_min[0][q * 64 + lane] = m0;
    s_min[1][q * 64 + lane] = m1;
    s_min[2][q * 64 + lane] = m2;
    s_min[3][q * 64 + lane] = m3;
    if (threadIdx.x < 16) s_cnt[threadIdx.x >> 2][threadIdx.x & 3] = 0;
    __syncthreads();
    {
        // wave q: per-lane min across the 4 source waves for center q, then
        // one bitonic. Each min-of-4 is still a single real point's d'.
        float v = fminf(fminf(s_min[q][lane], s_min[q][64 + lane]),
                        fminf(s_min[q][128 + lane], s_min[q][192 + lane]));
        float t = sixteenth_smallest(v, lane);
        if (lane == 0) s_T[q] = t;
    }
    __syncthreads();
    const float T0 = s_T[0], T1 = s_T[1], T2 = s_T[2], T3 = s_T[3];
    const float U0 = T0 + fabsf(T0) * 1e-5f + 5e-4f;
    const float U1 = T1 + fabsf(T1) * 1e-5f + 5e-4f;
    const float U2 = T2 + fabsf(T2) * 1e-5f + 5e-4f;
    const float U3 = T3 + fabsf(T3) * 1e-5f + 5e-4f;

    // ---- Phase 2: filter scan; divergent atomic compaction into LDS ----
#pragma unroll 2
    for (int s = 0; s < QGRP / 64; ++s) {
        int g = gbase + s * 64 + lane;
        float px[4], py[4], pz[4], xs[4];
        load_group(x4, g, px, py, pz, xs);
#pragma unroll
        for (int k = 0; k < 4; ++k) {
            float d0 = __fmaf_rn(px[k], n0[0], __fmaf_rn(py[k], n0[1], __fmaf_rn(pz[k], n0[2], xs[k])));
            float d1 = __fmaf_rn(px[k], n1[0], __fmaf_rn(py[k], n1[1], __fmaf_rn(pz[k], n1[2], xs[k])));
            float d2 = __fmaf_rn(px[k], n2[0], __fmaf_rn(py[k], n2[1], __fmaf_rn(pz[k], n2[2], xs[k])));
            float d3 = __fmaf_rn(px[k], n3[0], __fmaf_rn(py[k], n3[1], __fmaf_rn(pz[k], n3[2], xs[k])));
            int i = g * 4 + k;   // batch-local point index
            if (d0 <= U0) {
                int pos = atomicAdd(&s_cnt[0][q], 1);
                if (pos < HCAP) s_idx[0][q][pos] = (uint32_t)i;
            }
            if (d1 <= U1) {
                int pos = atomicAdd(&s_cnt[1][q], 1);
                if (pos < HCAP) s_idx[1][q][pos] = (uint32_t)i;
            }
            if (d2 <= U2) {
                int pos = atomicAdd(&s_cnt[2][q], 1);
                if (pos < HCAP) s_idx[2][q][pos] = (uint32_t)i;
            }
            if (d3 <= U3) {
                int pos = atomicAdd(&s_cnt[3][q], 1);
                if (pos < HCAP) s_idx[3][q][pos] = (uint32_t)i;
            }
        }
    }
    __syncthreads();

    // ---- Phase 3: wave q reranks center q exactly (no idle waves) ----
    const int cc = cbase + q;
    const float c0 = centers[cc * 3 + 0];
    const float c1 = centers[cc * 3 + 1];
    const float c2 = centers[cc * 3 + 2];
    const float csq = (c0 * c0 + c1 * c1) + c2 * c2;  // exact non-FMA reduce
    const int k0 = s_cnt[q][0], k1 = s_cnt[q][1], k2 = s_cnt[q][2], k3 = s_cnt[q][3];
    const int p1o = k0, p2o = k0 + k1, p3o = k0 + k1 + k2;
    const int total = p3o + k3;
    const bool ok = (k0 <= HCAP) & (k1 <= HCAP) & (k2 <= HCAP) & (k3 <= HCAP) &
                    (total <= 4 * 64);

    int res = 0;
    if (ok) {
        // Combined stream -> <= 4 keys/lane -> depth-4 list is exact.
        u64 l0 = ~0ull, l1 = ~0ull, l2 = ~0ull, l3 = ~0ull;
        for (int j = lane; j < total; j += 64) {
            int qq, off;
            if (j < p1o)      { qq = 0; off = j; }
            else if (j < p2o) { qq = 1; off = j - p1o; }
            else if (j < p3o) { qq = 2; off = j - p2o; }
            else              { qq = 3; off = j - p3o; }
            int idx = (int)s_idx[q][qq][off];
            float d2 = point_d2(xb, idx, c0, c1, c2, csq);
            u64 key = ((u64)__float_as_uint(__fsqrt_rn(d2)) << 32) | (u64)(uint32_t)idx;
            bool t;
            t = key < l0; { u64 lo = t ? key : l0, hi = t ? l0 : key; l0 = lo; key = hi; }
            t = key < l1; { u64 lo = t ? key : l1, hi = t ? l1 : key; l1 = lo; key = hi; }
            t = key < l2; { u64 lo = t ? key : l2, hi = t ? l2 : key; l2 = lo; key = hi; }
            t = key < l3; { u64 lo = t ? key : l3, hi = t ? l3 : key; l3 = lo; key = hi; }
        }
        for (int it = 0; it < KNN; ++it) {
            u64 best = wave_min_u64(l0);
            if (it == lane) res = (int)(uint32_t)best;
            if (l0 == best) { l0 = l1; l1 = l2; l2 = l3; l3 = ~0ull; }
        }
    } else {
        res = fallback_scan(xb, c0, c1, c2, csq, lane);
    }

    // out[b][rank][c_in_batch]
    if (lane < KNN) {
        out[((size_t)b * KNN + lane) * KK + (cc & 1023)] = res;
    }
}

extern "C" void kernel_launch(void* const* d_in, const int* in_sizes, int n_in,
                              void* d_out, int out_size, void* d_ws, size_t ws_size,
                              hipStream_t stream) {
    const float* xyz = (const float*)d_in[0];
    const float* centers = (const float*)d_in[1];
    int* out = (int*)d_out;
    (void)d_ws; (void)ws_size;

    const int nblocks = BB * KK / 4;   // 2048 blocks x 4 waves = 8192 waves (8/SIMD)
    hipLaunchKernelGGL(knn_kernel, dim3(nblocks), dim3(256), 0, stream,
                       xyz, centers, out);
}